// Round 3
// baseline (506.586 us; speedup 1.0000x reference)
//
#include <hip/hip_runtime.h>

// Problem constants
#define BB 4
#define SS 2048
#define DD 1024   // DIM_IN = DIM_Q = DIM_V = 1024

typedef __attribute__((ext_vector_type(8))) short short8;
typedef __attribute__((ext_vector_type(4))) float f32x4;

__device__ __forceinline__ unsigned short f2b(float f) {
  unsigned u = __builtin_bit_cast(unsigned, f);
  u += 0x7fffu + ((u >> 16) & 1u);   // RNE
  return (unsigned short)(u >> 16);
}
__device__ __forceinline__ float b2f(unsigned short us) {
  unsigned u = (unsigned)us << 16;
  return __builtin_bit_cast(float, u);
}

__device__ __forceinline__ void gl2lds16(const void* g, void* l) {
  __builtin_amdgcn_global_load_lds(
      (__attribute__((address_space(1))) unsigned int*)(void*)(size_t)(uintptr_t)g,
      (__attribute__((address_space(3))) unsigned int*)l, 16, 0, 0);
}

// -------- fp32 -> bf16 convert for 3 inputs (x<4096) and 3 weights (x>=4096)
__global__ __launch_bounds__(256) void cvt_all(
    const float* __restrict__ q, const float* __restrict__ k, const float* __restrict__ v,
    const float* __restrict__ wq, const float* __restrict__ wk, const float* __restrict__ wv,
    unsigned short* __restrict__ qo, unsigned short* __restrict__ ko, unsigned short* __restrict__ vo,
    unsigned short* __restrict__ wqo, unsigned short* __restrict__ wko, unsigned short* __restrict__ wvo) {
  const int z = blockIdx.z;
  const float* s;
  unsigned short* d;
  size_t i;
  if (blockIdx.x < 4096) {
    s = z == 0 ? q : (z == 1 ? k : v);
    d = z == 0 ? qo : (z == 1 ? ko : vo);
    i = (size_t)blockIdx.x * 2048 + threadIdx.x * 8;
  } else {
    s = z == 0 ? wq : (z == 1 ? wk : wv);
    d = z == 0 ? wqo : (z == 1 ? wko : wvo);
    i = (size_t)(blockIdx.x - 4096) * 2048 + threadIdx.x * 8;
  }
  float4 a = *(const float4*)(s + i);
  float4 b = *(const float4*)(s + i + 4);
  union { unsigned short us[8]; uint4 v4; } o;
  o.us[0] = f2b(a.x); o.us[1] = f2b(a.y); o.us[2] = f2b(a.z); o.us[3] = f2b(a.w);
  o.us[4] = f2b(b.x); o.us[5] = f2b(b.y); o.us[6] = f2b(b.z); o.us[7] = f2b(b.w);
  *(uint4*)(d + i) = o.v4;
}

// ================= 256x256 8-phase BT-layout bf16 GEMM =====================
// C[m][n] = sum_k A[m][k]*B[n][k].  BM=BN=256, BK=64, 512 threads (8 waves,
// 2x4), per-wave output 128x64.
//
// READ-AHEAD pipeline (round-3 restructure): phase p issues the ds_reads for
// phase p+1's MFMA into the frag set NOT consumed this phase, so the LDS pipe
// services reads concurrently with the matrix pipe's current 16-MFMA cluster.
// Round-2's in-phase read->lgkm0->MFMA consumption serialized LDS and MFMA
// (measured: 1300 cy/phase = 768 LDS + 620 MFMA, MfmaUtil 18%).
// Frag sets: fa0,fa1 (A halves, 8 short8 each), fb0,fb1 (B halves, 4 each) —
// each fragment read ONCE per K-tile (48KB/wave/iter, phases 4/8 balanced).
// NO manual lgkmcnt: the compiler inserts counted lgkm waits before first use
// of each frag (reads issued one phase + one barrier earlier => near-free).
//
// Phase shape: [reads(next)] [stage] [MFMA(cur)] [vmcnt(10)] [BAR]
// ONE barrier per phase. Cross-wave safety of stage-over-read: every region
// is staged exactly 2 phases after its last read; wave X's stage@p follows
// BAR(p-1) <= all waves issued MFMA(p-1) <= their reads(p-2) lgkm-drained.
//
// Stage ledger (iter i: MFMAs consume t0=2i in p1-4, t1=2i+1 in p5-8; stages
// write t2=t0+2, t3=t0+3; every region: stage@p, read@p+6):
//   p1: bA00<-t2   p2: bB00<-t2   p3: bB01<-t2   p4: bA01<-t2
//   p5: bA10<-t3   p6: bB10<-t3   p7: bB11<-t3   p8: bA11<-t3
// Reads (for NEXT phase): p1:bB01->fb1  p2:bA01->fa1  p3:bA10->fa0
//   p4:bB10->fb0  p5:bB11->fb1  p6:bA11->fa1  p7:bA00->fa0  p8:bB00->fb0
// vmcnt publish: steady state has 12 VMEM outstanding per wave (6 stage
// pairs); vmcnt(10) before each BAR retires exactly the 6-phase-old pair,
// publishing it for next phase's read. Prologue stages 8 pairs in ledger
// order then vmcnt(8) publishes the first 4 (bA00,bB00,bB01,bA01).
// Tail iter (no stages): queue drains 10->0 via vmcnt(8,6,4,2,0) at p1..p5.
//
// LDS: 8 distinct 16KB regions, 16x32-bf16 subtiles (1024B) with st_16x32
// XOR swizzle (byte ^= ((byte>>9)&1)<<5) applied as inverse-swizzled GLOBAL
// source + swizzled ds_read address (gl2lds dest stays linear). Verified
// conflict-free in rounds 1-2 (SQ_LDS_BANK_CONFLICT = 0).
enum { EPI_BIAS_COL = 0, EPI_BIAS_ROW = 1, EPI_SCORE = 2, EPI_OUT = 3 };

#define BAR() __builtin_amdgcn_s_barrier()
#define VMW10() asm volatile("s_waitcnt vmcnt(10)")
#define VMW8() asm volatile("s_waitcnt vmcnt(8)")
#define VMW6() asm volatile("s_waitcnt vmcnt(6)")
#define VMW4() asm volatile("s_waitcnt vmcnt(4)")
#define VMW2() asm volatile("s_waitcnt vmcnt(2)")
#define VMW0() asm volatile("s_waitcnt vmcnt(0)")

#define MMA(FA, FB, MH, NH)                                                    \
  do {                                                                         \
    __builtin_amdgcn_s_setprio(1);                                             \
    _Pragma("unroll") for (int mt = 0; mt < 4; ++mt)                           \
        _Pragma("unroll") for (int nt = 0; nt < 2; ++nt)                       \
            _Pragma("unroll") for (int ks = 0; ks < 2; ++ks)                   \
                acc[MH][NH][mt][nt] = __builtin_amdgcn_mfma_f32_16x16x32_bf16( \
                    FA[mt][ks], FB[nt][ks], acc[MH][NH][mt][nt], 0, 0, 0);     \
    __builtin_amdgcn_s_setprio(0);                                             \
  } while (0)

template <int EPI>
__global__ __launch_bounds__(512, 2) void gemm256(
    const unsigned short* __restrict__ A, int lda, long long aBatch,
    const unsigned short* __restrict__ Bm, int ldb, long long bBatch,
    void* __restrict__ Cv, int ldc, long long cBatch, int K,
    const float* __restrict__ bias,   // z==0 bias (or the only one)
    const float* __restrict__ bias2,  // z==1 bias for batched q/k dispatch
    float scale) {
  __shared__ __attribute__((aligned(1024))) char bA00[16384];
  __shared__ __attribute__((aligned(1024))) char bA01[16384];
  __shared__ __attribute__((aligned(1024))) char bA10[16384];
  __shared__ __attribute__((aligned(1024))) char bA11[16384];
  __shared__ __attribute__((aligned(1024))) char bB00[16384];
  __shared__ __attribute__((aligned(1024))) char bB01[16384];
  __shared__ __attribute__((aligned(1024))) char bB10[16384];
  __shared__ __attribute__((aligned(1024))) char bB11[16384];

  const int tid = threadIdx.x;
  const int wave = tid >> 6, lane = tid & 63;
  const int l15 = lane & 15, quad = lane >> 4;
  const int wr = wave >> 2, wc = wave & 3;   // 2x4 wave grid
  const int bm = blockIdx.x * 256, bn = blockIdx.y * 256, z = blockIdx.z;
  A += (long long)z * aBatch;
  Bm += (long long)z * bBatch;

  // ds_read byte offset within a 16x32 subtile for fragment (row=l15, k=quad*8):
  // (l15&15)*64 + quad*16, bit9 = l15&8 -> XOR byte bit5.
  const int laneterm = l15 * 64 + ((quad * 16) ^ ((l15 & 8) << 2));

  // Staging: dest slot s = tid + i*512 (16B units, linear). Source element =
  // linear element at slot s ^ (((s>>5)&1)<<1) (involution). 32-bit voffsets
  // so gl2lds uses SGPR base + VGPR voffset (saves ~30 VGPR of 64b addrs —
  // needed: frags now cost 96 VGPR and budget is 256/wave at 8 waves/CU).
  int avoff0, avoff1, bvoff0, bvoff1;
  int dst0, dst1;
  {
    int s = tid, s2 = s ^ (((s >> 5) & 1) << 1);
    int row = (s2 >> 7) * 16 + ((s2 >> 2) & 15);
    int col = ((s2 >> 6) & 1) * 32 + (s2 & 3) * 8;
    avoff0 = (bm + row) * lda + col;
    bvoff0 = (bn + row) * ldb + col;
    dst0 = (tid & ~63) * 16;            // wave-uniform; HW adds lane*16B
    s = tid + 512; s2 = s ^ (((s >> 5) & 1) << 1);
    row = (s2 >> 7) * 16 + ((s2 >> 2) & 15);
    col = ((s2 >> 6) & 1) * 32 + (s2 & 3) * 8;
    avoff1 = (bm + row) * lda + col;
    bvoff1 = (bn + row) * ldb + col;
    dst1 = dst0 + 8192;
  }

  auto stageA = [&](char* d, int half, int t) {
    const unsigned short* base = A + (size_t)(half * 128) * lda + (size_t)t * 64;
    gl2lds16(base + avoff0, d + dst0);
    gl2lds16(base + avoff1, d + dst1);
  };
  auto stageB = [&](char* d, int half, int t) {
    const unsigned short* base = Bm + (size_t)(half * 128) * ldb + (size_t)t * 64;
    gl2lds16(base + bvoff0, d + dst0);
    gl2lds16(base + bvoff1, d + dst1);
  };

  f32x4 acc[2][2][4][2] = {};       // [mh][nh][mt][nt]
  short8 fa0[4][2], fa1[4][2];      // A-half frag sets (8 reads each)
  short8 fb0[2][2], fb1[2][2];      // B-half frag sets (4 reads each)

  auto loadA = [&](const char* rg, short8 (&f)[4][2]) {
#pragma unroll
    for (int mt = 0; mt < 4; ++mt)
#pragma unroll
      for (int ks = 0; ks < 2; ++ks)
        f[mt][ks] = *(const short8*)(rg + ((wr * 4 + mt) * 2 + ks) * 1024 + laneterm);
  };
  auto loadB = [&](const char* rg, short8 (&f)[2][2]) {
#pragma unroll
    for (int nt = 0; nt < 2; ++nt)
#pragma unroll
      for (int ks = 0; ks < 2; ++ks)
        f[nt][ks] = *(const short8*)(rg + ((wc * 2 + nt) * 2 + ks) * 1024 + laneterm);
  };

  const int NT = K >> 6;   // K-tiles of 64
  const int NI = NT >> 1;  // iterations (2 K-tiles each)

  // Prologue: stage all 8 regions (t0=0, t1=1) in ledger order.
  stageA(bA00, 0, 0); stageB(bB00, 0, 0); stageB(bB01, 1, 0); stageA(bA01, 1, 0);
  stageA(bA10, 0, 1); stageB(bB10, 0, 1); stageB(bB11, 1, 1); stageA(bA11, 1, 1);
  VMW8();   // publish bA00,bB00,bB01,bA01
  BAR();
  loadA(bA00, fa0); loadB(bB00, fb0);

  for (int i = 0; i < NI - 1; ++i) {
    const int t2 = 2 * i + 2, t3 = 2 * i + 3;
    loadB(bB01, fb1); stageA(bA00, 0, t2); MMA(fa0, fb0, 0, 0); VMW10(); BAR();
    loadA(bA01, fa1); stageB(bB00, 0, t2); MMA(fa0, fb1, 0, 1); VMW10(); BAR();
    loadA(bA10, fa0); stageB(bB01, 1, t2); MMA(fa1, fb0, 1, 0); VMW10(); BAR();
    loadB(bB10, fb0); stageA(bA01, 1, t2); MMA(fa1, fb1, 1, 1); VMW10(); BAR();
    loadB(bB11, fb1); stageA(bA10, 0, t3); MMA(fa0, fb0, 0, 0); VMW10(); BAR();
    loadA(bA11, fa1); stageB(bB10, 0, t3); MMA(fa0, fb1, 0, 1); VMW10(); BAR();
    loadA(bA00, fa0); stageB(bB11, 1, t3); MMA(fa1, fb0, 1, 0); VMW10(); BAR();
    loadB(bB00, fb0); stageA(bA11, 1, t3); MMA(fa1, fb1, 1, 1); VMW10(); BAR();
  }
  {  // tail iteration: tiles NT-2, NT-1; no stages; drain queue 10->0
    loadB(bB01, fb1); MMA(fa0, fb0, 0, 0); VMW8(); BAR();
    loadA(bA01, fa1); MMA(fa0, fb1, 0, 1); VMW6(); BAR();
    loadA(bA10, fa0); MMA(fa1, fb0, 1, 0); VMW4(); BAR();
    loadB(bB10, fb0); MMA(fa1, fb1, 1, 1); VMW2(); BAR();
    loadB(bB11, fb1); MMA(fa0, fb0, 0, 0); VMW0(); BAR();
    loadA(bA11, fa1); MMA(fa0, fb1, 0, 1); BAR();
    MMA(fa1, fb0, 1, 0);
    MMA(fa1, fb1, 1, 1);
  }

  // C/D layout (16x16x32): col = lane&15, row = quad*4 + reg.
  const int r0 = bm + wr * 64 + quad * 4;
  const int c0 = bn + wc * 32 + l15;
  if constexpr (EPI == EPI_SCORE) {
    unsigned short* Cz = (unsigned short*)Cv + (long long)z * cBatch;
#pragma unroll
    for (int mh = 0; mh < 2; ++mh)
#pragma unroll
      for (int mt = 0; mt < 4; ++mt)
#pragma unroll
        for (int r = 0; r < 4; ++r) {
          const int row = r0 + mh * 128 + mt * 16 + r;
#pragma unroll
          for (int nh = 0; nh < 2; ++nh)
#pragma unroll
            for (int nt = 0; nt < 2; ++nt)
              Cz[(size_t)row * ldc + c0 + nh * 128 + nt * 16] =
                  f2b(acc[mh][nh][mt][nt][r] * scale);
        }
  } else if constexpr (EPI == EPI_OUT) {
    float* Cz = (float*)Cv + (long long)z * cBatch;
#pragma unroll
    for (int mh = 0; mh < 2; ++mh)
#pragma unroll
      for (int mt = 0; mt < 4; ++mt)
#pragma unroll
        for (int r = 0; r < 4; ++r) {
          const int row = r0 + mh * 128 + mt * 16 + r;
#pragma unroll
          for (int nh = 0; nh < 2; ++nh)
#pragma unroll
            for (int nt = 0; nt < 2; ++nt)
              Cz[(size_t)row * ldc + c0 + nh * 128 + nt * 16] = acc[mh][nh][mt][nt][r];
        }
  } else {
    const float* bp = (z == 0) ? bias : bias2;
    unsigned short* Cz = (unsigned short*)Cv + (long long)z * cBatch;
#pragma unroll
    for (int mh = 0; mh < 2; ++mh)
#pragma unroll
      for (int mt = 0; mt < 4; ++mt)
#pragma unroll
        for (int r = 0; r < 4; ++r) {
          const int row = r0 + mh * 128 + mt * 16 + r;
#pragma unroll
          for (int nh = 0; nh < 2; ++nh)
#pragma unroll
            for (int nt = 0; nt < 2; ++nt) {
              const int col = c0 + nh * 128 + nt * 16;
              float v = acc[mh][nh][mt][nt][r] +
                        (EPI == EPI_BIAS_COL ? bp[col] : bp[row]);
              Cz[(size_t)row * ldc + col] = f2b(v);
            }
        }
  }
}

// ------- row softmax: bf16 scores + raw mask (dtype self-probed) -> bf16 P --
__global__ __launch_bounds__(256) void softmax_rows(const unsigned short* __restrict__ Sc,
                                                    const void* __restrict__ mask,
                                                    unsigned short* __restrict__ P) {
  const size_t r = blockIdx.x;
  const unsigned short* src = Sc + r * SS;
  unsigned short* dst = P + r * SS;
  const int tid = threadIdx.x;
  const int wave = tid >> 6, lane = tid & 63;
  __shared__ int anyv[4];
  __shared__ float red[8];

  // dtype probe: first 256 words are inside row 0 for both layouts.
  unsigned pw = ((const unsigned*)mask)[tid];
  unsigned long long bal = __ballot(pw > 1u);
  if (lane == 0) anyv[wave] = (bal != 0ULL) ? 1 : 0;
  __syncthreads();
  const bool isU8 = (anyv[0] | anyv[1] | anyv[2] | anyv[3]) != 0;

  unsigned mbits = 0;
  if (isU8) {
    uint2 v = *(const uint2*)((const unsigned char*)mask + r * SS + tid * 8);
#pragma unroll
    for (int j = 0; j < 4; ++j) {
      mbits |= (((v.x >> (8 * j)) & 0xffu) ? 1u : 0u) << j;
      mbits |= (((v.y >> (8 * j)) & 0xffu) ? 1u : 0u) << (j + 4);
    }
  } else {
    const uint4* p = (const uint4*)((const int*)mask + r * SS + tid * 8);
    uint4 a = p[0], b = p[1];
    mbits = (a.x ? 1u : 0u) | ((a.y ? 1u : 0u) << 1) | ((a.z ? 1u : 0u) << 2) |
            ((a.w ? 1u : 0u) << 3) | ((b.x ? 1u : 0u) << 4) | ((b.y ? 1u : 0u) << 5) |
            ((b.z ? 1u : 0u) << 6) | ((b.w ? 1u : 0u) << 7);
  }

  union { unsigned short us[8]; uint4 v; } in;
  in.v = *(const uint4*)(src + tid * 8);
  float xs[8];
#pragma unroll
  for (int k = 0; k < 8; ++k)
    xs[k] = ((mbits >> k) & 1u) ? -1.0e9f : b2f(in.us[k]);
  float mx = xs[0];
#pragma unroll
  for (int k = 1; k < 8; ++k) mx = fmaxf(mx, xs[k]);
#pragma unroll
  for (int o = 32; o; o >>= 1) mx = fmaxf(mx, __shfl_xor(mx, o));
  if (lane == 0) red[wave] = mx;
  __syncthreads();
  mx = fmaxf(fmaxf(red[0], red[1]), fmaxf(red[2], red[3]));
  float e[8], s = 0.f;
#pragma unroll
  for (int k = 0; k < 8; ++k) { e[k] = __expf(xs[k] - mx); s += e[k]; }
#pragma unroll
  for (int o = 32; o; o >>= 1) s += __shfl_xor(s, o);
  if (lane == 0) red[4 + wave] = s;
  __syncthreads();
  s = (red[4] + red[5]) + (red[6] + red[7]);
  float inv = 1.0f / s;
  union { unsigned short us[8]; uint4 v; } o;
#pragma unroll
  for (int k = 0; k < 8; ++k) o.us[k] = f2b(e[k] * inv);
  *(uint4*)(dst + tid * 8) = o.v;
}

extern "C" void kernel_launch(void* const* d_in, const int* in_sizes, int n_in,
                              void* d_out, int out_size, void* d_ws, size_t ws_size,
                              hipStream_t stream) {
  const float* query = (const float*)d_in[0];
  const float* key   = (const float*)d_in[1];
  const float* value = (const float*)d_in[2];
  const void*  mask  = d_in[3];                 // bool: u8 or i32, self-probed
  const float* Wq = (const float*)d_in[4];
  const float* bq = (const float*)d_in[5];
  const float* Wk = (const float*)d_in[6];
  const float* bk = (const float*)d_in[7];
  const float* Wv = (const float*)d_in[8];
  const float* bv = (const float*)d_in[9];
  float* out = (float*)d_out;

  char* ws = (char*)d_ws;
  const size_t MB = 1024 * 1024;
  unsigned short* qin = (unsigned short*)(ws + 0 * MB);    // 8192x1024 bf16, 16MB
  unsigned short* kin = (unsigned short*)(ws + 16 * MB);
  unsigned short* vin = (unsigned short*)(ws + 32 * MB);
  unsigned short* Wqb = (unsigned short*)(ws + 48 * MB);   // 1024x1024 bf16, 2MB
  unsigned short* Wkb = (unsigned short*)(ws + 50 * MB);
  unsigned short* Wvb = (unsigned short*)(ws + 52 * MB);
  unsigned short* qb  = (unsigned short*)(ws + 54 * MB);   // q proj bf16, 16MB
  unsigned short* kb  = (unsigned short*)(ws + 70 * MB);
  unsigned short* vT  = (unsigned short*)(ws + 86 * MB);   // v^T [1024][8192] bf16
  unsigned short* Sc  = (unsigned short*)(ws + 102 * MB);  // scores bf16, 32MB
  unsigned short* P   = (unsigned short*)(ws + 134 * MB);  // softmax bf16, 32MB

  dim3 blk(256), blk512(512);

  // fp32 -> bf16 for all six tensors (one dispatch)
  cvt_all<<<dim3(4608, 1, 3), blk, 0, stream>>>(
      query, key, value, Wq, Wk, Wv, qin, kin, vin, Wqb, Wkb, Wvb);

  // q = query @ Wq^T + bq ; k = key @ Wk^T + bk   (batched z=2, bf16 out)
  gemm256<EPI_BIAS_COL><<<dim3(32, 4, 2), blk512, 0, stream>>>(
      qin, 1024, 8388608LL, Wqb, 1024, 1048576LL, qb, 1024, 8388608LL,
      1024, bq, bk, 0.f);

  // v^T[n][m] = sum_d Wv[n,d] * value[m,d] + bv[n]  -> [1024][8192] bf16
  gemm256<EPI_BIAS_ROW><<<dim3(4, 32, 1), blk512, 0, stream>>>(
      Wvb, 1024, 0, vin, 1024, 0, vT, 8192, 0, 1024, bv, bv, 0.f);

  // scores[b][m][n] = (q_m . k_n) / 32   (bf16, unmasked)
  gemm256<EPI_SCORE><<<dim3(8, 8, BB), blk512, 0, stream>>>(
      qb, 1024, (long long)SS * 1024, kb, 1024, (long long)SS * 1024,
      Sc, SS, (long long)SS * SS, 1024, nullptr, nullptr, 0.03125f);

  // P = softmax(mask ? -1e9 : scores) rows, bf16
  softmax_rows<<<dim3(BB * SS), blk, 0, stream>>>(Sc, mask, P);

  // out[b][m][n] = sum_k P[m][k] * vT[n][k]   (fp32 out)
  gemm256<EPI_OUT><<<dim3(8, 4, BB), blk512, 0, stream>>>(
      P, SS, (long long)SS * SS, vT, 8192, (long long)SS,
      out, 1024, (long long)SS * 1024, SS, nullptr, nullptr, 1.f);
}

// Round 5
// 369.919 us; speedup vs baseline: 1.3695x; 1.3695x over previous
//
#include <hip/hip_runtime.h>

// Problem constants
#define BB 4
#define SS 2048
#define DD 1024   // DIM_IN = DIM_Q = DIM_V = 1024

typedef __attribute__((ext_vector_type(8))) short short8;
typedef __attribute__((ext_vector_type(4))) float f32x4;

__device__ __forceinline__ unsigned short f2b(float f) {
  unsigned u = __builtin_bit_cast(unsigned, f);
  u += 0x7fffu + ((u >> 16) & 1u);   // RNE
  return (unsigned short)(u >> 16);
}
__device__ __forceinline__ float b2f(unsigned short us) {
  unsigned u = (unsigned)us << 16;
  return __builtin_bit_cast(float, u);
}

__device__ __forceinline__ void gl2lds16(const void* g, void* l) {
  __builtin_amdgcn_global_load_lds(
      (__attribute__((address_space(1))) unsigned int*)(void*)(size_t)(uintptr_t)g,
      (__attribute__((address_space(3))) unsigned int*)l, 16, 0, 0);
}

// -------- fp32 -> bf16 convert for 3 inputs (x<4096) and 3 weights (x>=4096)
__global__ __launch_bounds__(256) void cvt_all(
    const float* __restrict__ q, const float* __restrict__ k, const float* __restrict__ v,
    const float* __restrict__ wq, const float* __restrict__ wk, const float* __restrict__ wv,
    unsigned short* __restrict__ qo, unsigned short* __restrict__ ko, unsigned short* __restrict__ vo,
    unsigned short* __restrict__ wqo, unsigned short* __restrict__ wko, unsigned short* __restrict__ wvo) {
  const int z = blockIdx.z;
  const float* s;
  unsigned short* d;
  size_t i;
  if (blockIdx.x < 4096) {
    s = z == 0 ? q : (z == 1 ? k : v);
    d = z == 0 ? qo : (z == 1 ? ko : vo);
    i = (size_t)blockIdx.x * 2048 + threadIdx.x * 8;
  } else {
    s = z == 0 ? wq : (z == 1 ? wk : wv);
    d = z == 0 ? wqo : (z == 1 ? wko : wvo);
    i = (size_t)(blockIdx.x - 4096) * 2048 + threadIdx.x * 8;
  }
  float4 a = *(const float4*)(s + i);
  float4 b = *(const float4*)(s + i + 4);
  union { unsigned short us[8]; uint4 v4; } o;
  o.us[0] = f2b(a.x); o.us[1] = f2b(a.y); o.us[2] = f2b(a.z); o.us[3] = f2b(a.w);
  o.us[4] = f2b(b.x); o.us[5] = f2b(b.y); o.us[6] = f2b(b.z); o.us[7] = f2b(b.w);
  *(uint4*)(d + i) = o.v4;
}

// ---------------- BT-layout bf16 GEMM: C[m][n] = sum_k A[m][k]*B[n][k] -----
// 128x128 tile, BK=32, 256 threads (4 waves, each 64x64 via 4x4 MFMA 16x16x32)
//
// Round-5: DOUBLE-BUFFERED LDS (T3-minimum 2-phase). Round-0 was single-
// buffered: stage -> syncthreads (vmcnt0 drain right after issue = full
// global latency exposed every K-step) -> read+MFMA -> syncthreads.
// Now: ONE __syncthreads per K-step; stage of tile t+1 is issued BEFORE the
// reads/MFMA of tile t, so the implicit vmcnt(0) drain at the next barrier
// waits on ~600cy-old loads (latency hidden under compute). Hazard closure
// is entirely via __syncthreads semantics:
//   - buf[cur] ready at loop top: barrier drains each wave's own stages.
//   - stage@k+1 overwrites buf read@k: reads@k lgkm-drain before MFMA@k
//     (compiler-inserted), which precedes barrier@k+1, which precedes the
//     stage. No counted vmcnt, no raw barriers (rounds 1-4 post-mortem).
// LDS 32KB/block -> 2 blocks/CU at launch_bounds(256,2) unchanged.
//
// Rounds 1-4 (256x256 8-phase deep pipeline) are abandoned: correct versions
// measured 69us vs this structure's 57us baseline; the race-free variants of
// the deep schedule were never faster on this shape.
enum { EPI_BIAS_COL = 0, EPI_BIAS_ROW = 1, EPI_SCORE = 2, EPI_OUT = 3 };

// __launch_bounds__(256,2): round4<->5 A/B (prev session) showed (256,4)
// regresses the scores GEMM 55.8 -> 59.2 us with no occupancy gain. Keep 2.
template <int EPI>
__global__ __launch_bounds__(256, 2) void gemm_bt(
    const unsigned short* __restrict__ A, int lda, long long aBatch,
    const unsigned short* __restrict__ Bm, int ldb, long long bBatch,
    void* __restrict__ Cv, int ldc, long long cBatch,
    int K,
    const float* __restrict__ bias,   // z==0 bias (or the only one)
    const float* __restrict__ bias2,  // z==1 bias for batched q/k dispatch
    float scale) {
  __shared__ unsigned short sA[2][128 * 32];
  __shared__ unsigned short sB[2][128 * 32];
  const int tid  = threadIdx.x;
  const int wave = tid >> 6;
  const int lane = tid & 63;
  const int l15  = lane & 15;
  const int quad = lane >> 4;
  const int waveR = wave >> 1, waveC = wave & 1;
  const int bm = blockIdx.x * 128;
  const int bn = blockIdx.y * 128;
  const int z  = blockIdx.z;
  A  += (long long)z * aBatch;
  Bm += (long long)z * bBatch;

  const unsigned short* gA0 = A  + (size_t)(bm + (tid >> 2)) * lda + (tid & 3) * 8;
  const unsigned short* gA1 = gA0 + (size_t)64 * lda;
  const unsigned short* gB0 = Bm + (size_t)(bn + (tid >> 2)) * ldb + (tid & 3) * 8;
  const unsigned short* gB1 = gB0 + (size_t)64 * ldb;
  const int ldsOff = wave * 64 * 8;   // wave-uniform LDS base; HW adds lane*16B

  f32x4 acc[4][4] = {};

  const int aro = (waveR * 64 + l15) * 32 + quad * 8;
  const int bro = (waveC * 64 + l15) * 32 + quad * 8;

  auto stage = [&](int c, int kt) {
    unsigned short* lA = sA[c] + ldsOff;
    unsigned short* lB = sB[c] + ldsOff;
    gl2lds16(gA0 + kt, lA);
    gl2lds16(gA1 + kt, lA + 256 * 8);
    gl2lds16(gB0 + kt, lB);
    gl2lds16(gB1 + kt, lB + 256 * 8);
  };

  // Prologue: stage tile 0 into buffer 0.
  stage(0, 0);
  int cur = 0;

  for (int kt = 0; kt < K; kt += 32) {
    __syncthreads();                 // buf[cur] landed (drains own vmcnt to 0)
    if (kt + 32 < K) stage(cur ^ 1, kt + 32);   // prefetch next tile
    short8 af[4], bf[4];
#pragma unroll
    for (int i = 0; i < 4; ++i) af[i] = *(const short8*)(sA[cur] + aro + i * 16 * 32);
#pragma unroll
    for (int j = 0; j < 4; ++j) bf[j] = *(const short8*)(sB[cur] + bro + j * 16 * 32);
#pragma unroll
    for (int i = 0; i < 4; ++i)
#pragma unroll
      for (int j = 0; j < 4; ++j)
        acc[i][j] = __builtin_amdgcn_mfma_f32_16x16x32_bf16(af[i], bf[j], acc[i][j], 0, 0, 0);
    cur ^= 1;
  }

  // C/D layout: col = lane&15, row = quad*4 + reg
  const int r0 = bm + waveR * 64 + quad * 4;
  const int c0 = bn + waveC * 64 + l15;

  if constexpr (EPI == EPI_SCORE) {
    unsigned short* Cz = (unsigned short*)Cv + (long long)z * cBatch;
#pragma unroll
    for (int i = 0; i < 4; ++i)
#pragma unroll
      for (int r = 0; r < 4; ++r) {
        int row = r0 + i * 16 + r;
#pragma unroll
        for (int j = 0; j < 4; ++j) {
          int col = c0 + j * 16;
          Cz[(size_t)row * ldc + col] = f2b(acc[i][j][r] * scale);
        }
      }
  } else if constexpr (EPI == EPI_OUT) {
    float* Cz = (float*)Cv + (long long)z * cBatch;
#pragma unroll
    for (int i = 0; i < 4; ++i)
#pragma unroll
      for (int r = 0; r < 4; ++r) {
        int row = r0 + i * 16 + r;
#pragma unroll
        for (int j = 0; j < 4; ++j) {
          int col = c0 + j * 16;
          Cz[(size_t)row * ldc + col] = acc[i][j][r];
        }
      }
  } else {
    const float* bp = (z == 0) ? bias : bias2;
    unsigned short* Cz = (unsigned short*)Cv + (long long)z * cBatch;
#pragma unroll
    for (int i = 0; i < 4; ++i)
#pragma unroll
      for (int r = 0; r < 4; ++r) {
        int row = r0 + i * 16 + r;
#pragma unroll
        for (int j = 0; j < 4; ++j) {
          int col = c0 + j * 16;
          float v = acc[i][j][r] + (EPI == EPI_BIAS_COL ? bp[col] : bp[row]);
          Cz[(size_t)row * ldc + col] = f2b(v);
        }
      }
  }
}

// ------- row softmax: bf16 scores + raw mask (dtype self-probed) -> bf16 P --
__global__ __launch_bounds__(256) void softmax_rows(const unsigned short* __restrict__ Sc,
                                                    const void* __restrict__ mask,
                                                    unsigned short* __restrict__ P) {
  const size_t r = blockIdx.x;
  const unsigned short* src = Sc + r * SS;
  unsigned short* dst = P + r * SS;
  const int tid = threadIdx.x;
  const int wave = tid >> 6, lane = tid & 63;
  __shared__ int anyv[4];
  __shared__ float red[8];

  // dtype probe: first 256 words are inside row 0 for both layouts.
  // i32 bools -> all words 0/1. u8 packed bools -> word >1 w.p. 7/8.
  unsigned pw = ((const unsigned*)mask)[tid];
  unsigned long long bal = __ballot(pw > 1u);
  if (lane == 0) anyv[wave] = (bal != 0ULL) ? 1 : 0;
  __syncthreads();
  const bool isU8 = (anyv[0] | anyv[1] | anyv[2] | anyv[3]) != 0;

  // mask bits for cols [tid*8, tid*8+8)
  unsigned mbits = 0;
  if (isU8) {
    uint2 v = *(const uint2*)((const unsigned char*)mask + r * SS + tid * 8);
#pragma unroll
    for (int j = 0; j < 4; ++j) {
      mbits |= (((v.x >> (8 * j)) & 0xffu) ? 1u : 0u) << j;
      mbits |= (((v.y >> (8 * j)) & 0xffu) ? 1u : 0u) << (j + 4);
    }
  } else {
    const uint4* p = (const uint4*)((const int*)mask + r * SS + tid * 8);
    uint4 a = p[0], b = p[1];
    mbits = (a.x ? 1u : 0u) | ((a.y ? 1u : 0u) << 1) | ((a.z ? 1u : 0u) << 2) |
            ((a.w ? 1u : 0u) << 3) | ((b.x ? 1u : 0u) << 4) | ((b.y ? 1u : 0u) << 5) |
            ((b.z ? 1u : 0u) << 6) | ((b.w ? 1u : 0u) << 7);
  }

  union { unsigned short us[8]; uint4 v; } in;
  in.v = *(const uint4*)(src + tid * 8);
  float xs[8];
#pragma unroll
  for (int k = 0; k < 8; ++k)
    xs[k] = ((mbits >> k) & 1u) ? -1.0e9f : b2f(in.us[k]);
  float mx = xs[0];
#pragma unroll
  for (int k = 1; k < 8; ++k) mx = fmaxf(mx, xs[k]);
#pragma unroll
  for (int o = 32; o; o >>= 1) mx = fmaxf(mx, __shfl_xor(mx, o));
  if (lane == 0) red[wave] = mx;
  __syncthreads();
  mx = fmaxf(fmaxf(red[0], red[1]), fmaxf(red[2], red[3]));
  float e[8], s = 0.f;
#pragma unroll
  for (int k = 0; k < 8; ++k) { e[k] = __expf(xs[k] - mx); s += e[k]; }
#pragma unroll
  for (int o = 32; o; o >>= 1) s += __shfl_xor(s, o);
  if (lane == 0) red[4 + wave] = s;
  __syncthreads();
  s = (red[4] + red[5]) + (red[6] + red[7]);
  float inv = 1.0f / s;
  union { unsigned short us[8]; uint4 v; } o;
#pragma unroll
  for (int k = 0; k < 8; ++k) o.us[k] = f2b(e[k] * inv);
  *(uint4*)(dst + tid * 8) = o.v;
}

extern "C" void kernel_launch(void* const* d_in, const int* in_sizes, int n_in,
                              void* d_out, int out_size, void* d_ws, size_t ws_size,
                              hipStream_t stream) {
  const float* query = (const float*)d_in[0];
  const float* key   = (const float*)d_in[1];
  const float* value = (const float*)d_in[2];
  const void*  mask  = d_in[3];                 // bool: u8 or i32, self-probed
  const float* Wq = (const float*)d_in[4];
  const float* bq = (const float*)d_in[5];
  const float* Wk = (const float*)d_in[6];
  const float* bk = (const float*)d_in[7];
  const float* Wv = (const float*)d_in[8];
  const float* bv = (const float*)d_in[9];
  float* out = (float*)d_out;

  char* ws = (char*)d_ws;
  const size_t MB = 1024 * 1024;
  unsigned short* qin = (unsigned short*)(ws + 0 * MB);    // 8192x1024 bf16, 16MB
  unsigned short* kin = (unsigned short*)(ws + 16 * MB);   // (qin+z*8M for z batching)
  unsigned short* vin = (unsigned short*)(ws + 32 * MB);
  unsigned short* Wqb = (unsigned short*)(ws + 48 * MB);   // 1024x1024 bf16, 2MB
  unsigned short* Wkb = (unsigned short*)(ws + 50 * MB);   // (Wqb+z*1M)
  unsigned short* Wvb = (unsigned short*)(ws + 52 * MB);
  unsigned short* qb  = (unsigned short*)(ws + 54 * MB);   // q proj bf16, 16MB
  unsigned short* kb  = (unsigned short*)(ws + 70 * MB);   // (qb+z*8M)
  unsigned short* vT  = (unsigned short*)(ws + 86 * MB);   // v^T [1024][8192] bf16
  unsigned short* Sc  = (unsigned short*)(ws + 102 * MB);  // scores bf16, 32MB
  unsigned short* P   = (unsigned short*)(ws + 134 * MB);  // softmax bf16, 32MB

  dim3 blk(256);

  // fp32 -> bf16 for all six tensors (one dispatch)
  cvt_all<<<dim3(4608, 1, 3), blk, 0, stream>>>(
      query, key, value, Wq, Wk, Wv, qin, kin, vin, Wqb, Wkb, Wvb);

  // q = query @ Wq^T + bq ; k = key @ Wk^T + bk   (batched z=2, bf16 out)
  gemm_bt<EPI_BIAS_COL><<<dim3(64, 8, 2), blk, 0, stream>>>(
      qin, 1024, 8388608LL, Wqb, 1024, 1048576LL, qb, 1024, 8388608LL,
      1024, bq, bk, 0.f);

  // v^T[n][m] = sum_d Wv[n,d] * value[m,d] + bv[n]  -> [1024][8192] bf16
  gemm_bt<EPI_BIAS_ROW><<<dim3(8, 64, 1), blk, 0, stream>>>(
      Wvb, 1024, 0, vin, 1024, 0, vT, 8192, 0, 1024, bv, bv, 0.f);

  // scores[b][m][n] = (q_m . k_n) / 32   (bf16, unmasked)
  gemm_bt<EPI_SCORE><<<dim3(16, 16, BB), blk, 0, stream>>>(
      qb, 1024, (long long)SS * 1024, kb, 1024, (long long)SS * 1024,
      Sc, SS, (long long)SS * SS, 1024, nullptr, nullptr, 0.03125f);

  // P = softmax(mask ? -1e9 : scores) rows, bf16
  softmax_rows<<<dim3(BB * SS), blk, 0, stream>>>(Sc, mask, P);

  // out[b][m][n] = sum_k P[m][k] * vT[n][k]   (fp32 out)
  gemm_bt<EPI_OUT><<<dim3(16, 8, BB), blk, 0, stream>>>(
      P, SS, (long long)SS * SS, vT, 8192, (long long)SS,
      out, 1024, (long long)SS * 1024, SS, nullptr, nullptr, 1.f);
}

// Round 6
// 367.841 us; speedup vs baseline: 1.3772x; 1.0056x over previous
//
#include <hip/hip_runtime.h>

// Problem constants
#define BB 4
#define SS 2048
#define DD 1024   // DIM_IN = DIM_Q = DIM_V = 1024

typedef __attribute__((ext_vector_type(8))) short short8;
typedef __attribute__((ext_vector_type(4))) float f32x4;

__device__ __forceinline__ unsigned short f2b(float f) {
  unsigned u = __builtin_bit_cast(unsigned, f);
  u += 0x7fffu + ((u >> 16) & 1u);   // RNE
  return (unsigned short)(u >> 16);
}
__device__ __forceinline__ float b2f(unsigned short us) {
  unsigned u = (unsigned)us << 16;
  return __builtin_bit_cast(float, u);
}

__device__ __forceinline__ void gl2lds16(const void* g, void* l) {
  __builtin_amdgcn_global_load_lds(
      (__attribute__((address_space(1))) unsigned int*)(void*)(size_t)(uintptr_t)g,
      (__attribute__((address_space(3))) unsigned int*)l, 16, 0, 0);
}

// -------- fp32 -> bf16 convert for 3 inputs (x<4096) and 3 weights (x>=4096)
__global__ __launch_bounds__(256) void cvt_all(
    const float* __restrict__ q, const float* __restrict__ k, const float* __restrict__ v,
    const float* __restrict__ wq, const float* __restrict__ wk, const float* __restrict__ wv,
    unsigned short* __restrict__ qo, unsigned short* __restrict__ ko, unsigned short* __restrict__ vo,
    unsigned short* __restrict__ wqo, unsigned short* __restrict__ wko, unsigned short* __restrict__ wvo) {
  const int z = blockIdx.z;
  const float* s;
  unsigned short* d;
  size_t i;
  if (blockIdx.x < 4096) {
    s = z == 0 ? q : (z == 1 ? k : v);
    d = z == 0 ? qo : (z == 1 ? ko : vo);
    i = (size_t)blockIdx.x * 2048 + threadIdx.x * 8;
  } else {
    s = z == 0 ? wq : (z == 1 ? wk : wv);
    d = z == 0 ? wqo : (z == 1 ? wko : wvo);
    i = (size_t)(blockIdx.x - 4096) * 2048 + threadIdx.x * 8;
  }
  float4 a = *(const float4*)(s + i);
  float4 b = *(const float4*)(s + i + 4);
  union { unsigned short us[8]; uint4 v4; } o;
  o.us[0] = f2b(a.x); o.us[1] = f2b(a.y); o.us[2] = f2b(a.z); o.us[3] = f2b(a.w);
  o.us[4] = f2b(b.x); o.us[5] = f2b(b.y); o.us[6] = f2b(b.z); o.us[7] = f2b(b.w);
  *(uint4*)(d + i) = o.v4;
}

// ---------------- BT-layout bf16 GEMM: C[m][n] = sum_k A[m][k]*B[n][k] -----
// 128x128 tile, BK=32, 256 threads (4 waves, each 64x64 via 4x4 MFMA 16x16x32)
//
// Round-6: READS-BEFORE-STAGE ordering. Theory (from rounds 0/5 being exactly
// equal): when the stage (global_load_lds, tracked by vmcnt) is issued BEFORE
// the ds_reads of the other buffer, the compiler cannot disambiguate the DMA
// target (dynamic sA[cur^1]) from the read source (sA[cur]) and inserts a
// vmcnt(0) wait BEFORE the reads -> the prefetch is drained immediately after
// issue, every K-step, making dbuf == single-buffer (measured: both 57us).
// Fix: after __syncthreads, issue the 8 fragment ds_reads FIRST, then the
// stage, then MFMA. sched_barrier(0) fences pin the order (stage must not
// hoist above the reads nor sink below the MFMA cluster). The only vmcnt(0)
// left is inside __syncthreads, waiting on loads issued ~a full phase earlier
// (covered by reads-issue + 16-MFMA issue; panels are mostly L2-hits).
// Hazard closure unchanged from round 5, all via __syncthreads semantics:
//   - buf[cur] ready at loop top (barrier drains vmcnt to 0);
//   - stage@k overwrites buffer read@k-1: reads lgkm-drain before MFMA@k-1,
//     which precedes barrier@k, which precedes the stage.
enum { EPI_BIAS_COL = 0, EPI_BIAS_ROW = 1, EPI_SCORE = 2, EPI_OUT = 3 };

// __launch_bounds__(256,2): (256,4) measured regression in a prior session
// (55.8 -> 59.2 us scores GEMM). Keep 2.
template <int EPI>
__global__ __launch_bounds__(256, 2) void gemm_bt(
    const unsigned short* __restrict__ A, int lda, long long aBatch,
    const unsigned short* __restrict__ Bm, int ldb, long long bBatch,
    void* __restrict__ Cv, int ldc, long long cBatch,
    int K,
    const float* __restrict__ bias,   // z==0 bias (or the only one)
    const float* __restrict__ bias2,  // z==1 bias for batched q/k dispatch
    float scale) {
  __shared__ unsigned short sA[2][128 * 32];
  __shared__ unsigned short sB[2][128 * 32];
  const int tid  = threadIdx.x;
  const int wave = tid >> 6;
  const int lane = tid & 63;
  const int l15  = lane & 15;
  const int quad = lane >> 4;
  const int waveR = wave >> 1, waveC = wave & 1;
  const int bm = blockIdx.x * 128;
  const int bn = blockIdx.y * 128;
  const int z  = blockIdx.z;
  A  += (long long)z * aBatch;
  Bm += (long long)z * bBatch;

  const unsigned short* gA0 = A  + (size_t)(bm + (tid >> 2)) * lda + (tid & 3) * 8;
  const unsigned short* gA1 = gA0 + (size_t)64 * lda;
  const unsigned short* gB0 = Bm + (size_t)(bn + (tid >> 2)) * ldb + (tid & 3) * 8;
  const unsigned short* gB1 = gB0 + (size_t)64 * ldb;
  const int ldsOff = wave * 64 * 8;   // wave-uniform LDS base; HW adds lane*16B

  f32x4 acc[4][4] = {};

  const int aro = (waveR * 64 + l15) * 32 + quad * 8;
  const int bro = (waveC * 64 + l15) * 32 + quad * 8;

  auto stage = [&](int c, int kt) {
    unsigned short* lA = sA[c] + ldsOff;
    unsigned short* lB = sB[c] + ldsOff;
    gl2lds16(gA0 + kt, lA);
    gl2lds16(gA1 + kt, lA + 256 * 8);
    gl2lds16(gB0 + kt, lB);
    gl2lds16(gB1 + kt, lB + 256 * 8);
  };

  // Prologue: stage tile 0 into buffer 0 (this one's latency is exposed once).
  stage(0, 0);
  int cur = 0;

  for (int kt = 0; kt < K; kt += 32) {
    __syncthreads();                 // buf[cur] landed (vmcnt0+lgkm0+barrier)
    short8 af[4], bf[4];
#pragma unroll
    for (int i = 0; i < 4; ++i) af[i] = *(const short8*)(sA[cur] + aro + i * 16 * 32);
#pragma unroll
    for (int j = 0; j < 4; ++j) bf[j] = *(const short8*)(sB[cur] + bro + j * 16 * 32);
    __builtin_amdgcn_sched_barrier(0);   // reads issued before any new DMA
    if (kt + 32 < K) stage(cur ^ 1, kt + 32);   // prefetch next tile
    __builtin_amdgcn_sched_barrier(0);   // stage issued before MFMA cluster
#pragma unroll
    for (int i = 0; i < 4; ++i)
#pragma unroll
      for (int j = 0; j < 4; ++j)
        acc[i][j] = __builtin_amdgcn_mfma_f32_16x16x32_bf16(af[i], bf[j], acc[i][j], 0, 0, 0);
    cur ^= 1;
  }

  // C/D layout: col = lane&15, row = quad*4 + reg
  const int r0 = bm + waveR * 64 + quad * 4;
  const int c0 = bn + waveC * 64 + l15;

  if constexpr (EPI == EPI_SCORE) {
    unsigned short* Cz = (unsigned short*)Cv + (long long)z * cBatch;
#pragma unroll
    for (int i = 0; i < 4; ++i)
#pragma unroll
      for (int r = 0; r < 4; ++r) {
        int row = r0 + i * 16 + r;
#pragma unroll
        for (int j = 0; j < 4; ++j) {
          int col = c0 + j * 16;
          Cz[(size_t)row * ldc + col] = f2b(acc[i][j][r] * scale);
        }
      }
  } else if constexpr (EPI == EPI_OUT) {
    float* Cz = (float*)Cv + (long long)z * cBatch;
#pragma unroll
    for (int i = 0; i < 4; ++i)
#pragma unroll
      for (int r = 0; r < 4; ++r) {
        int row = r0 + i * 16 + r;
#pragma unroll
        for (int j = 0; j < 4; ++j) {
          int col = c0 + j * 16;
          Cz[(size_t)row * ldc + col] = acc[i][j][r];
        }
      }
  } else {
    const float* bp = (z == 0) ? bias : bias2;
    unsigned short* Cz = (unsigned short*)Cv + (long long)z * cBatch;
#pragma unroll
    for (int i = 0; i < 4; ++i)
#pragma unroll
      for (int r = 0; r < 4; ++r) {
        int row = r0 + i * 16 + r;
#pragma unroll
        for (int j = 0; j < 4; ++j) {
          int col = c0 + j * 16;
          float v = acc[i][j][r] + (EPI == EPI_BIAS_COL ? bp[col] : bp[row]);
          Cz[(size_t)row * ldc + col] = f2b(v);
        }
      }
  }
}

// ------- row softmax: bf16 scores + raw mask (dtype self-probed) -> bf16 P --
__global__ __launch_bounds__(256) void softmax_rows(const unsigned short* __restrict__ Sc,
                                                    const void* __restrict__ mask,
                                                    unsigned short* __restrict__ P) {
  const size_t r = blockIdx.x;
  const unsigned short* src = Sc + r * SS;
  unsigned short* dst = P + r * SS;
  const int tid = threadIdx.x;
  const int wave = tid >> 6, lane = tid & 63;
  __shared__ int anyv[4];
  __shared__ float red[8];

  // dtype probe: first 256 words are inside row 0 for both layouts.
  // i32 bools -> all words 0/1. u8 packed bools -> word >1 w.p. 7/8.
  unsigned pw = ((const unsigned*)mask)[tid];
  unsigned long long bal = __ballot(pw > 1u);
  if (lane == 0) anyv[wave] = (bal != 0ULL) ? 1 : 0;
  __syncthreads();
  const bool isU8 = (anyv[0] | anyv[1] | anyv[2] | anyv[3]) != 0;

  // mask bits for cols [tid*8, tid*8+8)
  unsigned mbits = 0;
  if (isU8) {
    uint2 v = *(const uint2*)((const unsigned char*)mask + r * SS + tid * 8);
#pragma unroll
    for (int j = 0; j < 4; ++j) {
      mbits |= (((v.x >> (8 * j)) & 0xffu) ? 1u : 0u) << j;
      mbits |= (((v.y >> (8 * j)) & 0xffu) ? 1u : 0u) << (j + 4);
    }
  } else {
    const uint4* p = (const uint4*)((const int*)mask + r * SS + tid * 8);
    uint4 a = p[0], b = p[1];
    mbits = (a.x ? 1u : 0u) | ((a.y ? 1u : 0u) << 1) | ((a.z ? 1u : 0u) << 2) |
            ((a.w ? 1u : 0u) << 3) | ((b.x ? 1u : 0u) << 4) | ((b.y ? 1u : 0u) << 5) |
            ((b.z ? 1u : 0u) << 6) | ((b.w ? 1u : 0u) << 7);
  }

  union { unsigned short us[8]; uint4 v; } in;
  in.v = *(const uint4*)(src + tid * 8);
  float xs[8];
#pragma unroll
  for (int k = 0; k < 8; ++k)
    xs[k] = ((mbits >> k) & 1u) ? -1.0e9f : b2f(in.us[k]);
  float mx = xs[0];
#pragma unroll
  for (int k = 1; k < 8; ++k) mx = fmaxf(mx, xs[k]);
#pragma unroll
  for (int o = 32; o; o >>= 1) mx = fmaxf(mx, __shfl_xor(mx, o));
  if (lane == 0) red[wave] = mx;
  __syncthreads();
  mx = fmaxf(fmaxf(red[0], red[1]), fmaxf(red[2], red[3]));
  float e[8], s = 0.f;
#pragma unroll
  for (int k = 0; k < 8; ++k) { e[k] = __expf(xs[k] - mx); s += e[k]; }
#pragma unroll
  for (int o = 32; o; o >>= 1) s += __shfl_xor(s, o);
  if (lane == 0) red[4 + wave] = s;
  __syncthreads();
  s = (red[4] + red[5]) + (red[6] + red[7]);
  float inv = 1.0f / s;
  union { unsigned short us[8]; uint4 v; } o;
#pragma unroll
  for (int k = 0; k < 8; ++k) o.us[k] = f2b(e[k] * inv);
  *(uint4*)(dst + tid * 8) = o.v;
}

extern "C" void kernel_launch(void* const* d_in, const int* in_sizes, int n_in,
                              void* d_out, int out_size, void* d_ws, size_t ws_size,
                              hipStream_t stream) {
  const float* query = (const float*)d_in[0];
  const float* key   = (const float*)d_in[1];
  const float* value = (const float*)d_in[2];
  const void*  mask  = d_in[3];                 // bool: u8 or i32, self-probed
  const float* Wq = (const float*)d_in[4];
  const float* bq = (const float*)d_in[5];
  const float* Wk = (const float*)d_in[6];
  const float* bk = (const float*)d_in[7];
  const float* Wv = (const float*)d_in[8];
  const float* bv = (const float*)d_in[9];
  float* out = (float*)d_out;

  char* ws = (char*)d_ws;
  const size_t MB = 1024 * 1024;
  unsigned short* qin = (unsigned short*)(ws + 0 * MB);    // 8192x1024 bf16, 16MB
  unsigned short* kin = (unsigned short*)(ws + 16 * MB);   // (qin+z*8M for z batching)
  unsigned short* vin = (unsigned short*)(ws + 32 * MB);
  unsigned short* Wqb = (unsigned short*)(ws + 48 * MB);   // 1024x1024 bf16, 2MB
  unsigned short* Wkb = (unsigned short*)(ws + 50 * MB);   // (Wqb+z*1M)
  unsigned short* Wvb = (unsigned short*)(ws + 52 * MB);
  unsigned short* qb  = (unsigned short*)(ws + 54 * MB);   // q proj bf16, 16MB
  unsigned short* kb  = (unsigned short*)(ws + 70 * MB);   // (qb+z*8M)
  unsigned short* vT  = (unsigned short*)(ws + 86 * MB);   // v^T [1024][8192] bf16
  unsigned short* Sc  = (unsigned short*)(ws + 102 * MB);  // scores bf16, 32MB
  unsigned short* P   = (unsigned short*)(ws + 134 * MB);  // softmax bf16, 32MB

  dim3 blk(256);

  // fp32 -> bf16 for all six tensors (one dispatch)
  cvt_all<<<dim3(4608, 1, 3), blk, 0, stream>>>(
      query, key, value, Wq, Wk, Wv, qin, kin, vin, Wqb, Wkb, Wvb);

  // q = query @ Wq^T + bq ; k = key @ Wk^T + bk   (batched z=2, bf16 out)
  gemm_bt<EPI_BIAS_COL><<<dim3(64, 8, 2), blk, 0, stream>>>(
      qin, 1024, 8388608LL, Wqb, 1024, 1048576LL, qb, 1024, 8388608LL,
      1024, bq, bk, 0.f);

  // v^T[n][m] = sum_d Wv[n,d] * value[m,d] + bv[n]  -> [1024][8192] bf16
  gemm_bt<EPI_BIAS_ROW><<<dim3(8, 64, 1), blk, 0, stream>>>(
      Wvb, 1024, 0, vin, 1024, 0, vT, 8192, 0, 1024, bv, bv, 0.f);

  // scores[b][m][n] = (q_m . k_n) / 32   (bf16, unmasked)
  gemm_bt<EPI_SCORE><<<dim3(16, 16, BB), blk, 0, stream>>>(
      qb, 1024, (long long)SS * 1024, kb, 1024, (long long)SS * 1024,
      Sc, SS, (long long)SS * SS, 1024, nullptr, nullptr, 0.03125f);

  // P = softmax(mask ? -1e9 : scores) rows, bf16
  softmax_rows<<<dim3(BB * SS), blk, 0, stream>>>(Sc, mask, P);

  // out[b][m][n] = sum_k P[m][k] * vT[n][k]   (fp32 out)
  gemm_bt<EPI_OUT><<<dim3(16, 8, BB), blk, 0, stream>>>(
      P, SS, (long long)SS * SS, vT, 8192, (long long)SS,
      out, 1024, (long long)SS * 1024, SS, nullptr, nullptr, 1.f);
}

// Round 7
// 364.014 us; speedup vs baseline: 1.3917x; 1.0105x over previous
//
#include <hip/hip_runtime.h>

// Problem constants
#define BB 4
#define SS 2048
#define DD 1024   // DIM_IN = DIM_Q = DIM_V = 1024

typedef __attribute__((ext_vector_type(8))) short short8;
typedef __attribute__((ext_vector_type(4))) float f32x4;

__device__ __forceinline__ unsigned short f2b(float f) {
  unsigned u = __builtin_bit_cast(unsigned, f);
  u += 0x7fffu + ((u >> 16) & 1u);   // RNE
  return (unsigned short)(u >> 16);
}
__device__ __forceinline__ float b2f(unsigned short us) {
  unsigned u = (unsigned)us << 16;
  return __builtin_bit_cast(float, u);
}

__device__ __forceinline__ void gl2lds16(const void* g, void* l) {
  __builtin_amdgcn_global_load_lds(
      (__attribute__((address_space(1))) unsigned int*)(void*)(size_t)(uintptr_t)g,
      (__attribute__((address_space(3))) unsigned int*)l, 16, 0, 0);
}

// -------- fp32 -> bf16 convert, 64B/thread (round-7: was 32B/thread at
// 3.26 TB/s combined; 4x float4 reads give more memory-level parallelism).
// x<2048: inputs (8M elems / 4096 per block); x>=2048: weights (1M / 4096).
__global__ __launch_bounds__(256) void cvt_all(
    const float* __restrict__ q, const float* __restrict__ k, const float* __restrict__ v,
    const float* __restrict__ wq, const float* __restrict__ wk, const float* __restrict__ wv,
    unsigned short* __restrict__ qo, unsigned short* __restrict__ ko, unsigned short* __restrict__ vo,
    unsigned short* __restrict__ wqo, unsigned short* __restrict__ wko, unsigned short* __restrict__ wvo) {
  const int z = blockIdx.z;
  const float* s;
  unsigned short* d;
  size_t i;
  if (blockIdx.x < 2048) {
    s = z == 0 ? q : (z == 1 ? k : v);
    d = z == 0 ? qo : (z == 1 ? ko : vo);
    i = (size_t)blockIdx.x * 4096 + threadIdx.x * 16;
  } else {
    s = z == 0 ? wq : (z == 1 ? wk : wv);
    d = z == 0 ? wqo : (z == 1 ? wko : wvo);
    i = (size_t)(blockIdx.x - 2048) * 4096 + threadIdx.x * 16;
  }
  float4 a = *(const float4*)(s + i);
  float4 b = *(const float4*)(s + i + 4);
  float4 c = *(const float4*)(s + i + 8);
  float4 e = *(const float4*)(s + i + 12);
  union { unsigned short us[8]; uint4 v4; } o0, o1;
  o0.us[0] = f2b(a.x); o0.us[1] = f2b(a.y); o0.us[2] = f2b(a.z); o0.us[3] = f2b(a.w);
  o0.us[4] = f2b(b.x); o0.us[5] = f2b(b.y); o0.us[6] = f2b(b.z); o0.us[7] = f2b(b.w);
  o1.us[0] = f2b(c.x); o1.us[1] = f2b(c.y); o1.us[2] = f2b(c.z); o1.us[3] = f2b(c.w);
  o1.us[4] = f2b(e.x); o1.us[5] = f2b(e.y); o1.us[6] = f2b(e.z); o1.us[7] = f2b(e.w);
  *(uint4*)(d + i) = o0.v4;
  *(uint4*)(d + i + 8) = o1.v4;
}

// ---------------- BT-layout bf16 GEMM: C[m][n] = sum_k A[m][k]*B[n][k] -----
// 128x128 tile, BK=32, 256 threads (4 waves, each 64x64 via 4x4 MFMA 16x16x32)
//
// Round-6 (kept): READS-BEFORE-STAGE. After __syncthreads, issue the 8
// fragment ds_reads FIRST, then the stage, then MFMA (sched_barrier(0)
// fences pin the order). Issuing the stage before the reads made the
// compiler drain vmcnt(0) before the reads (LDS-DMA vs ds_read may-alias),
// killing the prefetch every K-step (rounds 0/5 both 57us; round 6: 50us,
// MfmaUtil 23->26%).
//
// Round-7: LDS XOR-SWIZZLE (st_16x32, the involution measured conflict-free
// in rounds 1-2 on this same read geometry: SQ_LDS_BANK_CONFLICT 4.19M -> 0).
// Tile [128][32] bf16 = 8 stacked [16][32] subtiles (1024B). Physical byte
// ^= ((byte>>9)&1)<<5, i.e. col-group bit1 ^= row bit3:
//   read:  quad_sw = quad ^ ((l15 & 8) ? 2 : 0)
//   stage: source col-group = (tid&3) ^ ((tid & 32) >> 4)   (row = tid>>2)
// gl2lds dest stays linear (HW: wave-uniform base + lane*16B); the global
// SOURCE is pre-swizzled so physical slot p holds logical col p^key (both-
// sides-or-neither rule). Conflict math: lanes 0-15 (one quad) previously
// hit 2 bank-groups 8-way; now 4 groups (l15&1 x quad_sw bit1) -> measured
// zero in rounds 1-2.
enum { EPI_BIAS_COL = 0, EPI_BIAS_ROW = 1, EPI_SCORE = 2, EPI_OUT = 3 };

// __launch_bounds__(256,2): (256,4) measured regression in a prior session
// (55.8 -> 59.2 us scores GEMM). Keep 2.
template <int EPI>
__global__ __launch_bounds__(256, 2) void gemm_bt(
    const unsigned short* __restrict__ A, int lda, long long aBatch,
    const unsigned short* __restrict__ Bm, int ldb, long long bBatch,
    void* __restrict__ Cv, int ldc, long long cBatch,
    int K,
    const float* __restrict__ bias,   // z==0 bias (or the only one)
    const float* __restrict__ bias2,  // z==1 bias for batched q/k dispatch
    float scale) {
  __shared__ unsigned short sA[2][128 * 32];
  __shared__ unsigned short sB[2][128 * 32];
  const int tid  = threadIdx.x;
  const int wave = tid >> 6;
  const int lane = tid & 63;
  const int l15  = lane & 15;
  const int quad = lane >> 4;
  const int waveR = wave >> 1, waveC = wave & 1;
  const int bm = blockIdx.x * 128;
  const int bn = blockIdx.y * 128;
  const int z  = blockIdx.z;
  A  += (long long)z * aBatch;
  Bm += (long long)z * bBatch;

  // Stage source: row = tid>>2, col-group swizzled by row bit3 (= tid bit5).
  const int cg = ((tid & 3) ^ ((tid & 32) >> 4)) * 8;
  const unsigned short* gA0 = A  + (size_t)(bm + (tid >> 2)) * lda + cg;
  const unsigned short* gA1 = gA0 + (size_t)64 * lda;   // row+64: bit3 unchanged
  const unsigned short* gB0 = Bm + (size_t)(bn + (tid >> 2)) * ldb + cg;
  const unsigned short* gB1 = gB0 + (size_t)64 * ldb;
  const int ldsOff = wave * 64 * 8;   // wave-uniform LDS base; HW adds lane*16B

  f32x4 acc[4][4] = {};

  // Read: row = waveR*64 + i*16 + l15 (bit3 = l15&8), swizzled quad.
  const int qsw = quad ^ ((l15 & 8) ? 2 : 0);
  const int aro = (waveR * 64 + l15) * 32 + qsw * 8;
  const int bro = (waveC * 64 + l15) * 32 + qsw * 8;

  auto stage = [&](int c, int kt) {
    unsigned short* lA = sA[c] + ldsOff;
    unsigned short* lB = sB[c] + ldsOff;
    gl2lds16(gA0 + kt, lA);
    gl2lds16(gA1 + kt, lA + 256 * 8);
    gl2lds16(gB0 + kt, lB);
    gl2lds16(gB1 + kt, lB + 256 * 8);
  };

  // Prologue: stage tile 0 into buffer 0 (this one's latency is exposed once).
  stage(0, 0);
  int cur = 0;

  for (int kt = 0; kt < K; kt += 32) {
    __syncthreads();                 // buf[cur] landed (vmcnt0+lgkm0+barrier)
    short8 af[4], bf[4];
#pragma unroll
    for (int i = 0; i < 4; ++i) af[i] = *(const short8*)(sA[cur] + aro + i * 16 * 32);
#pragma unroll
    for (int j = 0; j < 4; ++j) bf[j] = *(const short8*)(sB[cur] + bro + j * 16 * 32);
    __builtin_amdgcn_sched_barrier(0);   // reads issued before any new DMA
    if (kt + 32 < K) stage(cur ^ 1, kt + 32);   // prefetch next tile
    __builtin_amdgcn_sched_barrier(0);   // stage issued before MFMA cluster
#pragma unroll
    for (int i = 0; i < 4; ++i)
#pragma unroll
      for (int j = 0; j < 4; ++j)
        acc[i][j] = __builtin_amdgcn_mfma_f32_16x16x32_bf16(af[i], bf[j], acc[i][j], 0, 0, 0);
    cur ^= 1;
  }

  // C/D layout: col = lane&15, row = quad*4 + reg
  const int r0 = bm + waveR * 64 + quad * 4;
  const int c0 = bn + waveC * 64 + l15;

  if constexpr (EPI == EPI_SCORE) {
    unsigned short* Cz = (unsigned short*)Cv + (long long)z * cBatch;
#pragma unroll
    for (int i = 0; i < 4; ++i)
#pragma unroll
      for (int r = 0; r < 4; ++r) {
        int row = r0 + i * 16 + r;
#pragma unroll
        for (int j = 0; j < 4; ++j) {
          int col = c0 + j * 16;
          Cz[(size_t)row * ldc + col] = f2b(acc[i][j][r] * scale);
        }
      }
  } else if constexpr (EPI == EPI_OUT) {
    float* Cz = (float*)Cv + (long long)z * cBatch;
#pragma unroll
    for (int i = 0; i < 4; ++i)
#pragma unroll
      for (int r = 0; r < 4; ++r) {
        int row = r0 + i * 16 + r;
#pragma unroll
        for (int j = 0; j < 4; ++j) {
          int col = c0 + j * 16;
          Cz[(size_t)row * ldc + col] = acc[i][j][r];
        }
      }
  } else {
    const float* bp = (z == 0) ? bias : bias2;
    unsigned short* Cz = (unsigned short*)Cv + (long long)z * cBatch;
#pragma unroll
    for (int i = 0; i < 4; ++i)
#pragma unroll
      for (int r = 0; r < 4; ++r) {
        int row = r0 + i * 16 + r;
#pragma unroll
        for (int j = 0; j < 4; ++j) {
          int col = c0 + j * 16;
          float v = acc[i][j][r] + (EPI == EPI_BIAS_COL ? bp[col] : bp[row]);
          Cz[(size_t)row * ldc + col] = f2b(v);
        }
      }
  }
}

// ------- row softmax: bf16 scores + raw mask (dtype self-probed) -> bf16 P --
__global__ __launch_bounds__(256) void softmax_rows(const unsigned short* __restrict__ Sc,
                                                    const void* __restrict__ mask,
                                                    unsigned short* __restrict__ P) {
  const size_t r = blockIdx.x;
  const unsigned short* src = Sc + r * SS;
  unsigned short* dst = P + r * SS;
  const int tid = threadIdx.x;
  const int wave = tid >> 6, lane = tid & 63;
  __shared__ int anyv[4];
  __shared__ float red[8];

  // dtype probe: first 256 words are inside row 0 for both layouts.
  // i32 bools -> all words 0/1. u8 packed bools -> word >1 w.p. 7/8.
  unsigned pw = ((const unsigned*)mask)[tid];
  unsigned long long bal = __ballot(pw > 1u);
  if (lane == 0) anyv[wave] = (bal != 0ULL) ? 1 : 0;
  __syncthreads();
  const bool isU8 = (anyv[0] | anyv[1] | anyv[2] | anyv[3]) != 0;

  // mask bits for cols [tid*8, tid*8+8)
  unsigned mbits = 0;
  if (isU8) {
    uint2 v = *(const uint2*)((const unsigned char*)mask + r * SS + tid * 8);
#pragma unroll
    for (int j = 0; j < 4; ++j) {
      mbits |= (((v.x >> (8 * j)) & 0xffu) ? 1u : 0u) << j;
      mbits |= (((v.y >> (8 * j)) & 0xffu) ? 1u : 0u) << (j + 4);
    }
  } else {
    const uint4* p = (const uint4*)((const int*)mask + r * SS + tid * 8);
    uint4 a = p[0], b = p[1];
    mbits = (a.x ? 1u : 0u) | ((a.y ? 1u : 0u) << 1) | ((a.z ? 1u : 0u) << 2) |
            ((a.w ? 1u : 0u) << 3) | ((b.x ? 1u : 0u) << 4) | ((b.y ? 1u : 0u) << 5) |
            ((b.z ? 1u : 0u) << 6) | ((b.w ? 1u : 0u) << 7);
  }

  union { unsigned short us[8]; uint4 v; } in;
  in.v = *(const uint4*)(src + tid * 8);
  float xs[8];
#pragma unroll
  for (int k = 0; k < 8; ++k)
    xs[k] = ((mbits >> k) & 1u) ? -1.0e9f : b2f(in.us[k]);
  float mx = xs[0];
#pragma unroll
  for (int k = 1; k < 8; ++k) mx = fmaxf(mx, xs[k]);
#pragma unroll
  for (int o = 32; o; o >>= 1) mx = fmaxf(mx, __shfl_xor(mx, o));
  if (lane == 0) red[wave] = mx;
  __syncthreads();
  mx = fmaxf(fmaxf(red[0], red[1]), fmaxf(red[2], red[3]));
  float e[8], s = 0.f;
#pragma unroll
  for (int k = 0; k < 8; ++k) { e[k] = __expf(xs[k] - mx); s += e[k]; }
#pragma unroll
  for (int o = 32; o; o >>= 1) s += __shfl_xor(s, o);
  if (lane == 0) red[4 + wave] = s;
  __syncthreads();
  s = (red[4] + red[5]) + (red[6] + red[7]);
  float inv = 1.0f / s;
  union { unsigned short us[8]; uint4 v; } o;
#pragma unroll
  for (int k = 0; k < 8; ++k) o.us[k] = f2b(e[k] * inv);
  *(uint4*)(dst + tid * 8) = o.v;
}

extern "C" void kernel_launch(void* const* d_in, const int* in_sizes, int n_in,
                              void* d_out, int out_size, void* d_ws, size_t ws_size,
                              hipStream_t stream) {
  const float* query = (const float*)d_in[0];
  const float* key   = (const float*)d_in[1];
  const float* value = (const float*)d_in[2];
  const void*  mask  = d_in[3];                 // bool: u8 or i32, self-probed
  const float* Wq = (const float*)d_in[4];
  const float* bq = (const float*)d_in[5];
  const float* Wk = (const float*)d_in[6];
  const float* bk = (const float*)d_in[7];
  const float* Wv = (const float*)d_in[8];
  const float* bv = (const float*)d_in[9];
  float* out = (float*)d_out;

  char* ws = (char*)d_ws;
  const size_t MB = 1024 * 1024;
  unsigned short* qin = (unsigned short*)(ws + 0 * MB);    // 8192x1024 bf16, 16MB
  unsigned short* kin = (unsigned short*)(ws + 16 * MB);   // (qin+z*8M for z batching)
  unsigned short* vin = (unsigned short*)(ws + 32 * MB);
  unsigned short* Wqb = (unsigned short*)(ws + 48 * MB);   // 1024x1024 bf16, 2MB
  unsigned short* Wkb = (unsigned short*)(ws + 50 * MB);   // (Wqb+z*1M)
  unsigned short* Wvb = (unsigned short*)(ws + 52 * MB);
  unsigned short* qb  = (unsigned short*)(ws + 54 * MB);   // q proj bf16, 16MB
  unsigned short* kb  = (unsigned short*)(ws + 70 * MB);   // (qb+z*8M)
  unsigned short* vT  = (unsigned short*)(ws + 86 * MB);   // v^T [1024][8192] bf16
  unsigned short* Sc  = (unsigned short*)(ws + 102 * MB);  // scores bf16, 32MB
  unsigned short* P   = (unsigned short*)(ws + 134 * MB);  // softmax bf16, 32MB

  dim3 blk(256);

  // fp32 -> bf16 for all six tensors (one dispatch, 64B/thread)
  cvt_all<<<dim3(2304, 1, 3), blk, 0, stream>>>(
      query, key, value, Wq, Wk, Wv, qin, kin, vin, Wqb, Wkb, Wvb);

  // q = query @ Wq^T + bq ; k = key @ Wk^T + bk   (batched z=2, bf16 out)
  gemm_bt<EPI_BIAS_COL><<<dim3(64, 8, 2), blk, 0, stream>>>(
      qin, 1024, 8388608LL, Wqb, 1024, 1048576LL, qb, 1024, 8388608LL,
      1024, bq, bk, 0.f);

  // v^T[n][m] = sum_d Wv[n,d] * value[m,d] + bv[n]  -> [1024][8192] bf16
  gemm_bt<EPI_BIAS_ROW><<<dim3(8, 64, 1), blk, 0, stream>>>(
      Wvb, 1024, 0, vin, 1024, 0, vT, 8192, 0, 1024, bv, bv, 0.f);

  // scores[b][m][n] = (q_m . k_n) / 32   (bf16, unmasked)
  gemm_bt<EPI_SCORE><<<dim3(16, 16, BB), blk, 0, stream>>>(
      qb, 1024, (long long)SS * 1024, kb, 1024, (long long)SS * 1024,
      Sc, SS, (long long)SS * SS, 1024, nullptr, nullptr, 0.03125f);

  // P = softmax(mask ? -1e9 : scores) rows, bf16
  softmax_rows<<<dim3(BB * SS), blk, 0, stream>>>(Sc, mask, P);

  // out[b][m][n] = sum_k P[m][k] * vT[n][k]   (fp32 out)
  gemm_bt<EPI_OUT><<<dim3(16, 8, BB), blk, 0, stream>>>(
      P, SS, (long long)SS * SS, vT, 8192, (long long)SS,
      out, 1024, (long long)SS * 1024, SS, nullptr, nullptr, 1.f);
}